// Round 6
// baseline (477.646 us; speedup 1.0000x reference)
//
#include <hip/hip_runtime.h>
#include <stdint.h>

// ---------- types ----------
typedef short bf16x8   __attribute__((ext_vector_type(8)));
typedef short short4v  __attribute__((ext_vector_type(4)));
typedef short short8v  __attribute__((ext_vector_type(8)));
typedef float f32x4    __attribute__((ext_vector_type(4)));

typedef __attribute__((address_space(3))) uint32_t lds_u32;
typedef const __attribute__((address_space(1))) uint32_t glob_u32;

__device__ __forceinline__ void gl_lds16(const void* g, void* l) {
  __builtin_amdgcn_global_load_lds((glob_u32*)g, (lds_u32*)l, 16, 0, 0);
}

__device__ __forceinline__ float bf2f(short u) {
  union { float f; uint32_t i; } v; v.i = ((uint32_t)(uint16_t)u) << 16; return v.f;
}
__device__ __forceinline__ short f2bf(float f) {
  union { float f; uint32_t i; } v; v.f = f;
  uint32_t r = v.i + 0x7FFFu + ((v.i >> 16) & 1u);
  return (short)(r >> 16);
}
__device__ __forceinline__ float siluf(float x) {
  return x * __builtin_amdgcn_rcpf(1.0f + __expf(-x));
}
__device__ __forceinline__ f32x4 mfma16(bf16x8 a, bf16x8 b, f32x4 c) {
  return __builtin_amdgcn_mfma_f32_16x16x32_bf16(a, b, c, 0, 0, 0);
}

// ---------- K1: LayerNorm(x) -> bf16 ----------
__global__ __launch_bounds__(256) void k_ln(const float* __restrict__ x, short* __restrict__ xn) {
  int row = blockIdx.x * 4 + (threadIdx.x >> 6);
  int lane = threadIdx.x & 63;
  const float4* xr = (const float4*)(x + (size_t)row * 512);
  float4 a = xr[lane * 2], b = xr[lane * 2 + 1];
  float s  = a.x + a.y + a.z + a.w + b.x + b.y + b.z + b.w;
  float s2 = a.x*a.x + a.y*a.y + a.z*a.z + a.w*a.w + b.x*b.x + b.y*b.y + b.z*b.z + b.w*b.w;
#pragma unroll
  for (int m = 1; m < 64; m <<= 1) { s += __shfl_xor(s, m); s2 += __shfl_xor(s2, m); }
  float mu = s * (1.f / 512.f);
  float rstd = rsqrtf(s2 * (1.f / 512.f) - mu * mu + 1e-6f);
  float v[8] = {a.x, a.y, a.z, a.w, b.x, b.y, b.z, b.w};
  short8v o;
#pragma unroll
  for (int j = 0; j < 8; ++j) o[j] = f2bf((v[j] - mu) * rstd);
  *(short8v*)&xn[(size_t)row * 512 + lane * 8] = o;
}

// ---------- K2: transpose+cast uvqk (512x2048) -> Wt (2048x512) bf16 ----------
__global__ __launch_bounds__(256) void k_prep_w(const float* __restrict__ uvqk, short* __restrict__ Wt) {
  __shared__ float t[64][65];
  int k0 = blockIdx.x * 64;
  int c0 = blockIdx.y * 64;
  for (int i = threadIdx.x; i < 64 * 64; i += 256) {
    int r = i >> 6, c = i & 63;
    t[r][c] = uvqk[(size_t)(k0 + r) * 2048 + c0 + c];
  }
  __syncthreads();
  for (int i = threadIdx.x; i < 64 * 64; i += 256) {
    int c = i >> 6, k = i & 63;
    Wt[(size_t)(c0 + c) * 512 + k0 + k] = f2bf(t[k][c]);
  }
}

// ---------- K2b: cast o_w ----------
__global__ __launch_bounds__(256) void k_cast_ow(const float* __restrict__ ow, short* __restrict__ owt) {
  int i = blockIdx.x * 256 + threadIdx.x;
  owt[i] = f2bf(ow[i]);
}

// ---------- K2c: streaming f32 -> bf16 cast (rpb / mask) ----------
__global__ __launch_bounds__(256) void k_cast_bf(const float* __restrict__ src, short* __restrict__ dst, int n8) {
  for (int i = blockIdx.x * 256 + threadIdx.x; i < n8; i += gridDim.x * 256) {
    const float4* s4 = (const float4*)src + (size_t)i * 2;
    float4 a = s4[0], b = s4[1];
    float v[8] = {a.x, a.y, a.z, a.w, b.x, b.y, b.z, b.w};
    short8v o;
#pragma unroll
    for (int j = 0; j < 8; ++j) o[j] = f2bf(v[j]);
    *(short8v*)&dst[(size_t)i * 8] = o;
  }
}

// ---------- shared GEMM core: 128x128 tile, K=512, BK=64, 4 waves ----------
__device__ __forceinline__ void gemm_core(const short* __restrict__ A, const short* __restrict__ Bt,
                                          int t0, int c0, short* As, short* Bs, f32x4 (&acc)[4][4]) {
  int tid = threadIdx.x;
  int w = tid >> 6, lane = tid & 63, l16 = lane & 15, lq = lane >> 4;
  int wm = (w >> 1) * 64, wn = (w & 1) * 64;
  int srow = tid >> 3;
  int sch = (tid & 7) ^ (srow & 7);
  const short* ag = A  + (size_t)(t0 + srow) * 512 + sch * 8;
  const short* bg = Bt + (size_t)(c0 + srow) * 512 + sch * 8;

  for (int k0 = 0; k0 < 512; k0 += 64) {
#pragma unroll
    for (int j = 0; j < 4; ++j) {
      gl_lds16(ag + (size_t)j * 32 * 512 + k0, (char*)As + j * 4096 + w * 1024);
      gl_lds16(bg + (size_t)j * 32 * 512 + k0, (char*)Bs + j * 4096 + w * 1024);
    }
    asm volatile("s_waitcnt vmcnt(0)" ::: "memory");
    __syncthreads();
#pragma unroll
    for (int kk = 0; kk < 2; ++kk) {
      bf16x8 af[4], bf[4];
#pragma unroll
      for (int mi = 0; mi < 4; ++mi) {
        int row = wm + mi * 16 + l16;
        af[mi] = *(const bf16x8*)&As[row * 64 + (((kk * 4 + lq) ^ (l16 & 7)) * 8)];
      }
#pragma unroll
      for (int ni = 0; ni < 4; ++ni) {
        int row = wn + ni * 16 + l16;
        bf[ni] = *(const bf16x8*)&Bs[row * 64 + (((kk * 4 + lq) ^ (l16 & 7)) * 8)];
      }
#pragma unroll
      for (int mi = 0; mi < 4; ++mi)
#pragma unroll
        for (int ni = 0; ni < 4; ++ni)
          acc[mi][ni] = mfma16(af[mi], bf[ni], acc[mi][ni]);
    }
    __syncthreads();
  }
}

// ---------- K3: proj = silu(xn @ Wt^T); v written transposed to Vt[b,h,d,n] ----------
__global__ __launch_bounds__(256) void k_gemm1(const short* __restrict__ A, const short* __restrict__ Bt,
                                               short* __restrict__ proj, short* __restrict__ Vt) {
  __shared__ short As[128 * 64], Bs[128 * 64];
  int c0 = blockIdx.x * 128, t0 = blockIdx.y * 128;
  f32x4 acc[4][4] = {};
  gemm_core(A, Bt, t0, c0, As, Bs, acc);
  int tid = threadIdx.x, w = tid >> 6, lane = tid & 63, l16 = lane & 15, lq = lane >> 4;
  int wm = (w >> 1) * 64, wn = (w & 1) * 64;
  bool isv = (c0 >= 512 && c0 < 1024);
#pragma unroll
  for (int mi = 0; mi < 4; ++mi)
#pragma unroll
    for (int ni = 0; ni < 4; ++ni) {
      int c = c0 + wn + ni * 16 + l16;
      int trow = t0 + wm + mi * 16 + lq * 4;
      if (isv) {
        int hh = (c - 512) >> 6, d = (c - 512) & 63;
        int bb = trow >> 11, nn = trow & 2047;
        short4v pv;
#pragma unroll
        for (int i = 0; i < 4; ++i) pv[i] = f2bf(siluf(acc[mi][ni][i]));
        *(short4v*)&Vt[((size_t)(bb * 8 + hh) * 64 + d) * 2048 + nn] = pv;
      } else {
#pragma unroll
        for (int i = 0; i < 4; ++i)
          proj[(size_t)(trow + i) * 2048 + c] = f2bf(siluf(acc[mi][ni][i]));
      }
    }
}

// ---------- K4: fused attention ----------
// Round-4 validated structure (swapped QK^T, Ps LDS, double-buffered K/V, 1 barrier/iter)
// + cross-iteration register prefetch of rpb/mask behind counted vmcnt(16)
// + optional bf16 rpb/mask (template).
template<bool BF>
__global__ __launch_bounds__(256, 3) void k_attn(const short* __restrict__ proj,
                                                 const short* __restrict__ Vt,
                                                 const void* __restrict__ rpbp,
                                                 const void* __restrict__ maskp,
                                                 float* __restrict__ attn) {
  __shared__ __align__(16) short Ks[2][64 * 64];   // [buf][kv][d], 16B-chunk ^= kv&7
  __shared__ __align__(16) short Vs[2][64 * 64];   // [buf][d][kv], 16B-chunk ^= d&7
  __shared__ __align__(16) short Ps[128 * 64];     // [q][kv] bf16, 16B-chunk ^= (q&7)

  int p = blockIdx.x;
  int L = (p & 7) * 128 + (p >> 3);   // chunked XCD swizzle (1024 % 8 == 0)
  int qt = L >> 6, h = (L >> 3) & 7, b = L & 7;
  int n0 = qt * 128;

  int tid = threadIdx.x;
  int w = tid >> 6, lane = tid & 63, l16 = lane & 15, lq = lane >> 4;

  // Q fragments (B-operand of swapped QK: col = l16 = q)
  bf16x8 qf[2][2];
#pragma unroll
  for (int mi = 0; mi < 2; ++mi)
#pragma unroll
    for (int kk = 0; kk < 2; ++kk) {
      int n = n0 + w * 32 + mi * 16 + l16;
      qf[mi][kk] = *(const bf16x8*)&proj[(size_t)(b * 2048 + n) * 2048 + 1024 + h * 64 + kk * 32 + lq * 8];
    }

  // staging lane constants (pre-swizzled global source -> linear LDS dest)
  int j8 = lane >> 3, c8 = lane & 7;
  int srcc = (c8 ^ j8) * 8;
  const short* kg = proj + (size_t)(b * 2048) * 2048 + 1536 + h * 64 + srcc;
  const short* vg = Vt + (size_t)((b * 8 + h) * 64) * 2048 + srcc;

  // rpb/mask per-thread element base: (q = n0+w*32+mi*16+l16, kv = kv0+ni*16+lq*4+i)
  size_t rbase = (size_t)h * 4194304 + (size_t)(n0 + w * 32 + l16) * 2048 + lq * 4;
  size_t mbase = (size_t)b * 4194304 + (size_t)(n0 + w * 32 + l16) * 2048 + lq * 4;

  f32x4 acc_o[2][4] = {};

  short4v rvb[2][4], mvb[2][4];   // bf16 prefetch regs
  f32x4   rvf[2][4], mvf[2][4];   // fp32 prefetch regs

  // ---- prologue: stage buf0 + prefetch rpb/mask for t=0 ----
#pragma unroll
  for (int j = 0; j < 2; ++j) {
    gl_lds16(kg + (size_t)(w * 16 + j * 8 + j8) * 2048, &Ks[0][w * 1024 + j * 512]);
    gl_lds16(vg + (size_t)(w * 16 + j * 8 + j8) * 2048, &Vs[0][w * 1024 + j * 512]);
  }
  __builtin_amdgcn_sched_barrier(0);
#pragma unroll
  for (int mi = 0; mi < 2; ++mi)
#pragma unroll
    for (int ni = 0; ni < 4; ++ni) {
      size_t off = (size_t)mi * 16 * 2048 + ni * 16;
      if constexpr (BF) {
        rvb[mi][ni] = *(const short4v*)((const short*)rpbp + rbase + off);
        mvb[mi][ni] = *(const short4v*)((const short*)maskp + mbase + off);
      } else {
        rvf[mi][ni] = *(const f32x4*)((const float*)rpbp + rbase + off);
        mvf[mi][ni] = *(const f32x4*)((const float*)maskp + mbase + off);
      }
    }
  __builtin_amdgcn_sched_barrier(0);
  asm volatile("s_waitcnt vmcnt(16)" ::: "memory");   // drain the 4 gl_lds only
  __builtin_amdgcn_sched_barrier(0);
  __builtin_amdgcn_s_barrier();

  for (int t = 0; t < 32; ++t) {
    int kv0 = t << 6;
    const short* Kc = Ks[t & 1];
    const short* Vc = Vs[t & 1];

    // (a) stage next K/V tile
    if (t < 31) {
      short* Kn = Ks[(t & 1) ^ 1];
      short* Vn = Vs[(t & 1) ^ 1];
      int kvn = kv0 + 64;
#pragma unroll
      for (int j = 0; j < 2; ++j) {
        gl_lds16(kg + (size_t)(kvn + w * 16 + j * 8 + j8) * 2048, &Kn[w * 1024 + j * 512]);
        gl_lds16(vg + (size_t)(w * 16 + j * 8 + j8) * 2048 + kvn, &Vn[w * 1024 + j * 512]);
      }
    }
    __builtin_amdgcn_sched_barrier(0);

    // (b) QK^T (swapped: A = K rows = kv, B = Q cols = q)
    f32x4 s[4][2];
#pragma unroll
    for (int ni = 0; ni < 4; ++ni)
#pragma unroll
      for (int mi = 0; mi < 2; ++mi) s[ni][mi] = (f32x4){0.f, 0.f, 0.f, 0.f};
    __builtin_amdgcn_s_setprio(1);
#pragma unroll
    for (int kk = 0; kk < 2; ++kk) {
      bf16x8 kf[4];
#pragma unroll
      for (int ni = 0; ni < 4; ++ni)
        kf[ni] = *(const bf16x8*)&Kc[(ni * 16 + l16) * 64 + (((kk * 4 + lq) ^ (l16 & 7)) * 8)];
#pragma unroll
      for (int ni = 0; ni < 4; ++ni)
#pragma unroll
        for (int mi = 0; mi < 2; ++mi)
          s[ni][mi] = mfma16(kf[ni], qf[mi][kk], s[ni][mi]);
    }
    __builtin_amdgcn_s_setprio(0);

    // (c) epilogue: p = silu(s + rpb) * mask -> Ps (short4v, swizzled); rpb/mask from regs
#pragma unroll
    for (int mi = 0; mi < 2; ++mi) {
      int row = w * 32 + mi * 16 + l16;
      char* pr = (char*)Ps + row * 128;
      int swz = (l16 & 7) << 4;
#pragma unroll
      for (int ni = 0; ni < 4; ++ni) {
        short4v pk;
#pragma unroll
        for (int i = 0; i < 4; ++i) {
          float r, m;
          if constexpr (BF) { r = bf2f(rvb[mi][ni][i]); m = bf2f(mvb[mi][ni][i]); }
          else              { r = rvf[mi][ni][i];       m = mvf[mi][ni][i]; }
          float xx = s[ni][mi][i] + r;
          pk[i] = f2bf(siluf(xx) * m);
        }
        *(short4v*)(pr + ((ni * 32 + lq * 8) ^ swz)) = pk;
      }
    }

    // (d) PV (Ps rows wave-private; compiler orders LDS deps)
    __builtin_amdgcn_s_setprio(1);
#pragma unroll
    for (int ks = 0; ks < 2; ++ks) {
      bf16x8 pf[2], vf[4];
#pragma unroll
      for (int mi = 0; mi < 2; ++mi) {
        int rp = w * 32 + mi * 16 + l16;
        pf[mi] = *(const bf16x8*)((const char*)Ps + rp * 128 + (((ks * 4 + lq) << 4) ^ ((l16 & 7) << 4)));
      }
#pragma unroll
      for (int ni = 0; ni < 4; ++ni)
        vf[ni] = *(const bf16x8*)&Vc[(ni * 16 + l16) * 64 + (((ks * 4 + lq) ^ (l16 & 7)) * 8)];
#pragma unroll
      for (int mi = 0; mi < 2; ++mi)
#pragma unroll
        for (int ni = 0; ni < 4; ++ni)
          acc_o[mi][ni] = mfma16(pf[mi], vf[ni], acc_o[mi][ni]);
    }
    __builtin_amdgcn_s_setprio(0);

    // (e) prefetch rpb/mask for t+1 (full-iteration latency cover)
    __builtin_amdgcn_sched_barrier(0);
    {
      int kvp = (t < 31) ? kv0 + 64 : kv0;
#pragma unroll
      for (int mi = 0; mi < 2; ++mi)
#pragma unroll
        for (int ni = 0; ni < 4; ++ni) {
          size_t off = (size_t)mi * 16 * 2048 + kvp + ni * 16;
          if constexpr (BF) {
            rvb[mi][ni] = *(const short4v*)((const short*)rpbp + rbase + off);
            mvb[mi][ni] = *(const short4v*)((const short*)maskp + mbase + off);
          } else {
            rvf[mi][ni] = *(const f32x4*)((const float*)rpbp + rbase + off);
            mvf[mi][ni] = *(const f32x4*)((const float*)maskp + mbase + off);
          }
        }
    }
    __builtin_amdgcn_sched_barrier(0);
    // (f) drain only the gl_lds; the 16 prefetch loads stay in flight across the barrier
    asm volatile("s_waitcnt vmcnt(16)" ::: "memory");
    __builtin_amdgcn_sched_barrier(0);
    __builtin_amdgcn_s_barrier();
  }

#pragma unroll
  for (int mi = 0; mi < 2; ++mi)
#pragma unroll
    for (int ni = 0; ni < 4; ++ni)
#pragma unroll
      for (int i = 0; i < 4; ++i) {
        int n = n0 + w * 32 + mi * 16 + lq * 4 + i;
        attn[(size_t)(b * 2048 + n) * 512 + h * 64 + ni * 16 + l16] = acc_o[mi][ni][i];
      }
}

// ---------- K5: gated = u * LayerNorm(attn) -> bf16 ----------
__global__ __launch_bounds__(256) void k_gate(const float* __restrict__ attn, const short* __restrict__ proj,
                                              short* __restrict__ gated) {
  int row = blockIdx.x * 4 + (threadIdx.x >> 6);
  int lane = threadIdx.x & 63;
  const float4* ar = (const float4*)(attn + (size_t)row * 512);
  float4 a = ar[lane * 2], b = ar[lane * 2 + 1];
  float s  = a.x + a.y + a.z + a.w + b.x + b.y + b.z + b.w;
  float s2 = a.x*a.x + a.y*a.y + a.z*a.z + a.w*a.w + b.x*b.x + b.y*b.y + b.z*b.z + b.w*b.w;
#pragma unroll
  for (int m = 1; m < 64; m <<= 1) { s += __shfl_xor(s, m); s2 += __shfl_xor(s2, m); }
  float mu = s * (1.f / 512.f);
  float rstd = rsqrtf(s2 * (1.f / 512.f) - mu * mu + 1e-6f);
  float v[8] = {a.x, a.y, a.z, a.w, b.x, b.y, b.z, b.w};
  short8v u = *(const short8v*)&proj[(size_t)row * 2048 + lane * 8];
  short8v g;
#pragma unroll
  for (int j = 0; j < 8; ++j) g[j] = f2bf(bf2f(u[j]) * ((v[j] - mu) * rstd));
  *(short8v*)&gated[(size_t)row * 512 + lane * 8] = g;
}

// ---------- K6: out = gated @ owt^T + o_b + x ----------
__global__ __launch_bounds__(256) void k_gemm2(const short* __restrict__ A, const short* __restrict__ Bt,
                                               const float* __restrict__ ob, const float* __restrict__ x,
                                               float* __restrict__ out) {
  __shared__ short As[128 * 64], Bs[128 * 64];
  int c0 = blockIdx.x * 128, t0 = blockIdx.y * 128;
  f32x4 acc[4][4] = {};
  gemm_core(A, Bt, t0, c0, As, Bs, acc);
  int tid = threadIdx.x, w = tid >> 6, lane = tid & 63, l16 = lane & 15, lq = lane >> 4;
  int wm = (w >> 1) * 64, wn = (w & 1) * 64;
#pragma unroll
  for (int mi = 0; mi < 4; ++mi)
#pragma unroll
    for (int ni = 0; ni < 4; ++ni) {
      int e = c0 + wn + ni * 16 + l16;
      float bias = ob[e];
#pragma unroll
      for (int i = 0; i < 4; ++i) {
        int t = t0 + wm + mi * 16 + lq * 4 + i;
        out[(size_t)t * 512 + e] = acc[mi][ni][i] + bias + x[(size_t)t * 512 + e];
      }
    }
}

// ---------- launch ----------
extern "C" void kernel_launch(void* const* d_in, const int* in_sizes, int n_in,
                              void* d_out, int out_size, void* d_ws, size_t ws_size,
                              hipStream_t stream) {
  const float* x    = (const float*)d_in[0];
  const float* rpb  = (const float*)d_in[1];
  const float* mask = (const float*)d_in[2];
  const float* uvqk = (const float*)d_in[3];
  const float* o_w  = (const float*)d_in[4];
  const float* o_b  = (const float*)d_in[5];
  float* out = (float*)d_out;

  char* p = (char*)d_ws;
  short* xn   = (short*)p; p += 16384ull * 512 * 2;       // 16 MB (reused as gated)
  short* Wt   = (short*)p; p += 2048ull * 512 * 2;        // 2 MB
  short* owt  = (short*)p; p += 512ull * 512 * 2;         // 0.5 MB
  short* proj = (short*)p; p += 16384ull * 2048 * 2;      // 64 MB
  short* Vt   = (short*)p; p += 8ull * 8 * 64 * 2048 * 2; // 16 MB
  float* attn = (float*)p; p += 16384ull * 512 * 4;       // 32 MB
  short* rpbh = (short*)p; p += 33554432ull * 2;          // 64 MB (bf16 rpb)
  short* mskh = (short*)p; p += 33554432ull * 2;          // 64 MB (bf16 mask)
  short* gated = xn;

  bool bf_ok = ws_size >= (size_t)((char*)p - (char*)d_ws);

  k_ln    <<<4096, 256, 0, stream>>>(x, xn);
  k_prep_w<<<dim3(8, 32), 256, 0, stream>>>(uvqk, Wt);
  k_cast_ow<<<1024, 256, 0, stream>>>(o_w, owt);
  if (bf_ok) {
    k_cast_bf<<<4096, 256, 0, stream>>>(rpb,  rpbh, 33554432 / 8);
    k_cast_bf<<<4096, 256, 0, stream>>>(mask, mskh, 33554432 / 8);
  }
  k_gemm1 <<<dim3(16, 128), 256, 0, stream>>>(xn, Wt, proj, Vt);
  if (bf_ok)
    k_attn<true> <<<1024, 256, 0, stream>>>(proj, Vt, rpbh, mskh, attn);
  else
    k_attn<false><<<1024, 256, 0, stream>>>(proj, Vt, rpb, mask, attn);
  k_gate  <<<4096, 256, 0, stream>>>(attn, proj, gated);
  k_gemm2 <<<dim3(4, 128), 256, 0, stream>>>(gated, owt, o_b, x, out);
}

// Round 7
// 412.817 us; speedup vs baseline: 1.1570x; 1.1570x over previous
//
#include <hip/hip_runtime.h>
#include <stdint.h>

// ---------- types ----------
typedef short bf16x8   __attribute__((ext_vector_type(8)));
typedef short short4v  __attribute__((ext_vector_type(4)));
typedef short short8v  __attribute__((ext_vector_type(8)));
typedef float f32x4    __attribute__((ext_vector_type(4)));

typedef __attribute__((address_space(3))) uint32_t lds_u32;
typedef const __attribute__((address_space(1))) uint32_t glob_u32;

__device__ __forceinline__ void gl_lds16(const void* g, void* l) {
  __builtin_amdgcn_global_load_lds((glob_u32*)g, (lds_u32*)l, 16, 0, 0);
}

__device__ __forceinline__ float bf2f(short u) {
  union { float f; uint32_t i; } v; v.i = ((uint32_t)(uint16_t)u) << 16; return v.f;
}
__device__ __forceinline__ short f2bf(float f) {
  union { float f; uint32_t i; } v; v.f = f;
  uint32_t r = v.i + 0x7FFFu + ((v.i >> 16) & 1u);
  return (short)(r >> 16);
}
__device__ __forceinline__ float siluf(float x) {
  return x * __builtin_amdgcn_rcpf(1.0f + __expf(-x));
}
__device__ __forceinline__ f32x4 mfma16(bf16x8 a, bf16x8 b, f32x4 c) {
  return __builtin_amdgcn_mfma_f32_16x16x32_bf16(a, b, c, 0, 0, 0);
}
__device__ __forceinline__ uint32_t cvtpk_bf16(float lo, float hi) {
  uint32_t d;
  asm("v_cvt_pk_bf16_f32 %0, %1, %2" : "=v"(d) : "v"(lo), "v"(hi));
  return d;
}

// ---------- K1: LayerNorm(x) -> bf16 ----------
__global__ __launch_bounds__(256) void k_ln(const float* __restrict__ x, short* __restrict__ xn) {
  int row = blockIdx.x * 4 + (threadIdx.x >> 6);
  int lane = threadIdx.x & 63;
  const float4* xr = (const float4*)(x + (size_t)row * 512);
  float4 a = xr[lane * 2], b = xr[lane * 2 + 1];
  float s  = a.x + a.y + a.z + a.w + b.x + b.y + b.z + b.w;
  float s2 = a.x*a.x + a.y*a.y + a.z*a.z + a.w*a.w + b.x*b.x + b.y*b.y + b.z*b.z + b.w*b.w;
#pragma unroll
  for (int m = 1; m < 64; m <<= 1) { s += __shfl_xor(s, m); s2 += __shfl_xor(s2, m); }
  float mu = s * (1.f / 512.f);
  float rstd = rsqrtf(s2 * (1.f / 512.f) - mu * mu + 1e-6f);
  float v[8] = {a.x, a.y, a.z, a.w, b.x, b.y, b.z, b.w};
  short8v o;
#pragma unroll
  for (int j = 0; j < 8; ++j) o[j] = f2bf((v[j] - mu) * rstd);
  *(short8v*)&xn[(size_t)row * 512 + lane * 8] = o;
}

// ---------- K2: transpose+cast uvqk (512x2048) -> Wt (2048x512) bf16 ----------
__global__ __launch_bounds__(256) void k_prep_w(const float* __restrict__ uvqk, short* __restrict__ Wt) {
  __shared__ float t[64][65];
  int k0 = blockIdx.x * 64;
  int c0 = blockIdx.y * 64;
  for (int i = threadIdx.x; i < 64 * 64; i += 256) {
    int r = i >> 6, c = i & 63;
    t[r][c] = uvqk[(size_t)(k0 + r) * 2048 + c0 + c];
  }
  __syncthreads();
  for (int i = threadIdx.x; i < 64 * 64; i += 256) {
    int c = i >> 6, k = i & 63;
    Wt[(size_t)(c0 + c) * 512 + k0 + k] = f2bf(t[k][c]);
  }
}

// ---------- K2b: cast o_w ----------
__global__ __launch_bounds__(256) void k_cast_ow(const float* __restrict__ ow, short* __restrict__ owt) {
  int i = blockIdx.x * 256 + threadIdx.x;
  owt[i] = f2bf(ow[i]);
}

// ---------- shared GEMM core: 128x128 tile, K=512, BK=64, 4 waves ----------
__device__ __forceinline__ void gemm_core(const short* __restrict__ A, const short* __restrict__ Bt,
                                          int t0, int c0, short* As, short* Bs, f32x4 (&acc)[4][4]) {
  int tid = threadIdx.x;
  int w = tid >> 6, lane = tid & 63, l16 = lane & 15, lq = lane >> 4;
  int wm = (w >> 1) * 64, wn = (w & 1) * 64;
  int srow = tid >> 3;
  int sch = (tid & 7) ^ (srow & 7);
  const short* ag = A  + (size_t)(t0 + srow) * 512 + sch * 8;
  const short* bg = Bt + (size_t)(c0 + srow) * 512 + sch * 8;

  for (int k0 = 0; k0 < 512; k0 += 64) {
#pragma unroll
    for (int j = 0; j < 4; ++j) {
      gl_lds16(ag + (size_t)j * 32 * 512 + k0, (char*)As + j * 4096 + w * 1024);
      gl_lds16(bg + (size_t)j * 32 * 512 + k0, (char*)Bs + j * 4096 + w * 1024);
    }
    asm volatile("s_waitcnt vmcnt(0)" ::: "memory");
    __syncthreads();
#pragma unroll
    for (int kk = 0; kk < 2; ++kk) {
      bf16x8 af[4], bf[4];
#pragma unroll
      for (int mi = 0; mi < 4; ++mi) {
        int row = wm + mi * 16 + l16;
        af[mi] = *(const bf16x8*)&As[row * 64 + (((kk * 4 + lq) ^ (l16 & 7)) * 8)];
      }
#pragma unroll
      for (int ni = 0; ni < 4; ++ni) {
        int row = wn + ni * 16 + l16;
        bf[ni] = *(const bf16x8*)&Bs[row * 64 + (((kk * 4 + lq) ^ (l16 & 7)) * 8)];
      }
#pragma unroll
      for (int mi = 0; mi < 4; ++mi)
#pragma unroll
        for (int ni = 0; ni < 4; ++ni)
          acc[mi][ni] = mfma16(af[mi], bf[ni], acc[mi][ni]);
    }
    __syncthreads();
  }
}

// ---------- K3: proj = silu(xn @ Wt^T); v written transposed to Vt[b,h,d,n] ----------
__global__ __launch_bounds__(256) void k_gemm1(const short* __restrict__ A, const short* __restrict__ Bt,
                                               short* __restrict__ proj, short* __restrict__ Vt) {
  __shared__ short As[128 * 64], Bs[128 * 64];
  int c0 = blockIdx.x * 128, t0 = blockIdx.y * 128;
  f32x4 acc[4][4] = {};
  gemm_core(A, Bt, t0, c0, As, Bs, acc);
  int tid = threadIdx.x, w = tid >> 6, lane = tid & 63, l16 = lane & 15, lq = lane >> 4;
  int wm = (w >> 1) * 64, wn = (w & 1) * 64;
  bool isv = (c0 >= 512 && c0 < 1024);
#pragma unroll
  for (int mi = 0; mi < 4; ++mi)
#pragma unroll
    for (int ni = 0; ni < 4; ++ni) {
      int c = c0 + wn + ni * 16 + l16;
      int trow = t0 + wm + mi * 16 + lq * 4;
      if (isv) {
        int hh = (c - 512) >> 6, d = (c - 512) & 63;
        int bb = trow >> 11, nn = trow & 2047;
        short4v pv;
#pragma unroll
        for (int i = 0; i < 4; ++i) pv[i] = f2bf(siluf(acc[mi][ni][i]));
        *(short4v*)&Vt[((size_t)(bb * 8 + hh) * 64 + d) * 2048 + nn] = pv;
      } else {
#pragma unroll
        for (int i = 0; i < 4; ++i)
          proj[(size_t)(trow + i) * 2048 + c] = f2bf(siluf(acc[mi][ni][i]));
      }
    }
}

// ---------- K4: fused attention ----------
// BQ=64 (16 q-rows/wave, 4 waves), BKV=64, double-buffered K/V, 1 barrier/iter.
// 40KB LDS -> 4 blocks/CU. Swapped QK^T (S-frag = rpb/mask order, float4 loads,
// cross-iteration register prefetch behind counted vmcnt(8)). Ps via cvt_pk.
__global__ __launch_bounds__(256, 4) void k_attn(const short* __restrict__ proj,
                                                 const short* __restrict__ Vt,
                                                 const float* __restrict__ rpb,
                                                 const float* __restrict__ maskp,
                                                 float* __restrict__ attn) {
  __shared__ __align__(16) short Ks[2][64 * 64];   // [buf][kv][d], 16B-chunk ^= kv&7
  __shared__ __align__(16) short Vs[2][64 * 64];   // [buf][d][kv], 16B-chunk ^= d&7
  __shared__ __align__(16) short Ps[64 * 64];      // [q][kv] bf16, 16B-chunk ^= (q&7)

  int p = blockIdx.x;                  // 2048 blocks
  int L = (p & 7) * 256 + (p >> 3);    // chunked XCD swizzle (2048 % 8 == 0)
  int qt = L >> 6, h = (L >> 3) & 7, b = L & 7;
  int n0 = qt * 64;

  int tid = threadIdx.x;
  int w = tid >> 6, lane = tid & 63, l16 = lane & 15, lq = lane >> 4;

  // Q fragments (B-operand of swapped QK: col = l16 = q); wave owns rows n0+w*16..+15
  bf16x8 qf[2];
#pragma unroll
  for (int kk = 0; kk < 2; ++kk) {
    int n = n0 + w * 16 + l16;
    qf[kk] = *(const bf16x8*)&proj[(size_t)(b * 2048 + n) * 2048 + 1024 + h * 64 + kk * 32 + lq * 8];
  }

  // staging lane constants (pre-swizzled global source -> linear LDS dest)
  int j8 = lane >> 3, c8 = lane & 7;
  int srcc = (c8 ^ j8) * 8;
  const short* kg = proj + (size_t)(b * 2048) * 2048 + 1536 + h * 64 + srcc;
  const short* vg = Vt + (size_t)((b * 8 + h) * 64) * 2048 + srcc;

  // rpb/mask per-thread element base: (q = n0+w*16+l16, kv = kv0+ni*16+lq*4+i)
  const float* rp_t = rpb   + (size_t)h * 4194304 + (size_t)(n0 + w * 16 + l16) * 2048 + lq * 4;
  const float* mk_t = maskp + (size_t)b * 4194304 + (size_t)(n0 + w * 16 + l16) * 2048 + lq * 4;

  f32x4 acc_o[4] = {};
  f32x4 rv[4], mv[4];

  // ---- prologue: stage buf0 + prefetch rpb/mask for t=0 ----
#pragma unroll
  for (int j = 0; j < 2; ++j) {
    gl_lds16(kg + (size_t)(w * 16 + j * 8 + j8) * 2048, &Ks[0][w * 1024 + j * 512]);
    gl_lds16(vg + (size_t)(w * 16 + j * 8 + j8) * 2048, &Vs[0][w * 1024 + j * 512]);
  }
  __builtin_amdgcn_sched_barrier(0);
#pragma unroll
  for (int ni = 0; ni < 4; ++ni) {
    rv[ni] = *(const f32x4*)(rp_t + ni * 16);
    mv[ni] = *(const f32x4*)(mk_t + ni * 16);
  }
  __builtin_amdgcn_sched_barrier(0);
  asm volatile("s_waitcnt vmcnt(8)" ::: "memory");   // drain the 4 gl_lds only
  __builtin_amdgcn_sched_barrier(0);
  __builtin_amdgcn_s_barrier();

  for (int t = 0; t < 32; ++t) {
    int kv0 = t << 6;
    const short* Kc = Ks[t & 1];
    const short* Vc = Vs[t & 1];

    // (a) stage next K/V tile
    if (t < 31) {
      short* Kn = Ks[(t & 1) ^ 1];
      short* Vn = Vs[(t & 1) ^ 1];
      int kvn = kv0 + 64;
#pragma unroll
      for (int j = 0; j < 2; ++j) {
        gl_lds16(kg + (size_t)(kvn + w * 16 + j * 8 + j8) * 2048, &Kn[w * 1024 + j * 512]);
        gl_lds16(vg + (size_t)(w * 16 + j * 8 + j8) * 2048 + kvn, &Vn[w * 1024 + j * 512]);
      }
    }
    __builtin_amdgcn_sched_barrier(0);

    // (b) QK^T (swapped: A = K rows = kv, B = Q cols = q)
    f32x4 s[4];
#pragma unroll
    for (int ni = 0; ni < 4; ++ni) s[ni] = (f32x4){0.f, 0.f, 0.f, 0.f};
    __builtin_amdgcn_s_setprio(1);
#pragma unroll
    for (int kk = 0; kk < 2; ++kk) {
      bf16x8 kf[4];
#pragma unroll
      for (int ni = 0; ni < 4; ++ni)
        kf[ni] = *(const bf16x8*)&Kc[(ni * 16 + l16) * 64 + (((kk * 4 + lq) ^ (l16 & 7)) * 8)];
#pragma unroll
      for (int ni = 0; ni < 4; ++ni)
        s[ni] = mfma16(kf[ni], qf[kk], s[ni]);
    }
    __builtin_amdgcn_s_setprio(0);

    // (c) epilogue: p = silu(s + rpb) * mask -> Ps (cvt_pk packed, swizzled)
    {
      int row = w * 16 + l16;
      char* pr = (char*)Ps + row * 128;
      int swz = (l16 & 7) << 4;
#pragma unroll
      for (int ni = 0; ni < 4; ++ni) {
        float pv[4];
#pragma unroll
        for (int i = 0; i < 4; ++i) {
          float xx = s[ni][i] + rv[ni][i];
          pv[i] = siluf(xx) * mv[ni][i];
        }
        union { uint32_t u[2]; short4v sv; } pk;
        pk.u[0] = cvtpk_bf16(pv[0], pv[1]);
        pk.u[1] = cvtpk_bf16(pv[2], pv[3]);
        *(short4v*)(pr + ((ni * 32 + lq * 8) ^ swz)) = pk.sv;
      }
    }

    // (d) PV (Ps rows wave-private; compiler orders LDS deps)
    __builtin_amdgcn_s_setprio(1);
#pragma unroll
    for (int ks = 0; ks < 2; ++ks) {
      bf16x8 pf, vf[4];
      {
        int rp = w * 16 + l16;
        pf = *(const bf16x8*)((const char*)Ps + rp * 128 + (((ks * 4 + lq) << 4) ^ ((l16 & 7) << 4)));
      }
#pragma unroll
      for (int ni = 0; ni < 4; ++ni)
        vf[ni] = *(const bf16x8*)&Vc[(ni * 16 + l16) * 64 + (((ks * 4 + lq) ^ (l16 & 7)) * 8)];
#pragma unroll
      for (int ni = 0; ni < 4; ++ni)
        acc_o[ni] = mfma16(pf, vf[ni], acc_o[ni]);
    }
    __builtin_amdgcn_s_setprio(0);

    // (e) prefetch rpb/mask for t+1 (full-iteration latency cover)
    __builtin_amdgcn_sched_barrier(0);
    {
      int kvp = (t < 31) ? kv0 + 64 : kv0;
#pragma unroll
      for (int ni = 0; ni < 4; ++ni) {
        rv[ni] = *(const f32x4*)(rp_t + kvp + ni * 16);
        mv[ni] = *(const f32x4*)(mk_t + kvp + ni * 16);
      }
    }
    __builtin_amdgcn_sched_barrier(0);
    // (f) drain only the 4 gl_lds; the 8 prefetch loads stay in flight across the barrier
    asm volatile("s_waitcnt vmcnt(8)" ::: "memory");
    __builtin_amdgcn_sched_barrier(0);
    __builtin_amdgcn_s_barrier();
  }

  // store: q = n0 + w*16 + lq*4 + i (D-frag row), d = ni*16 + l16 (D-frag col)
#pragma unroll
  for (int ni = 0; ni < 4; ++ni)
#pragma unroll
    for (int i = 0; i < 4; ++i) {
      int n = n0 + w * 16 + lq * 4 + i;
      attn[(size_t)(b * 2048 + n) * 512 + h * 64 + ni * 16 + l16] = acc_o[ni][i];
    }
}

// ---------- K5: gated = u * LayerNorm(attn) -> bf16 ----------
__global__ __launch_bounds__(256) void k_gate(const float* __restrict__ attn, const short* __restrict__ proj,
                                              short* __restrict__ gated) {
  int row = blockIdx.x * 4 + (threadIdx.x >> 6);
  int lane = threadIdx.x & 63;
  const float4* ar = (const float4*)(attn + (size_t)row * 512);
  float4 a = ar[lane * 2], b = ar[lane * 2 + 1];
  float s  = a.x + a.y + a.z + a.w + b.x + b.y + b.z + b.w;
  float s2 = a.x*a.x + a.y*a.y + a.z*a.z + a.w*a.w + b.x*b.x + b.y*b.y + b.z*b.z + b.w*b.w;
#pragma unroll
  for (int m = 1; m < 64; m <<= 1) { s += __shfl_xor(s, m); s2 += __shfl_xor(s2, m); }
  float mu = s * (1.f / 512.f);
  float rstd = rsqrtf(s2 * (1.f / 512.f) - mu * mu + 1e-6f);
  float v[8] = {a.x, a.y, a.z, a.w, b.x, b.y, b.z, b.w};
  short8v u = *(const short8v*)&proj[(size_t)row * 2048 + lane * 8];
  short8v g;
#pragma unroll
  for (int j = 0; j < 8; ++j) g[j] = f2bf(bf2f(u[j]) * ((v[j] - mu) * rstd));
  *(short8v*)&gated[(size_t)row * 512 + lane * 8] = g;
}

// ---------- K6: out = gated @ owt^T + o_b + x ----------
__global__ __launch_bounds__(256) void k_gemm2(const short* __restrict__ A, const short* __restrict__ Bt,
                                               const float* __restrict__ ob, const float* __restrict__ x,
                                               float* __restrict__ out) {
  __shared__ short As[128 * 64], Bs[128 * 64];
  int c0 = blockIdx.x * 128, t0 = blockIdx.y * 128;
  f32x4 acc[4][4] = {};
  gemm_core(A, Bt, t0, c0, As, Bs, acc);
  int tid = threadIdx.x, w = tid >> 6, lane = tid & 63, l16 = lane & 15, lq = lane >> 4;
  int wm = (w >> 1) * 64, wn = (w & 1) * 64;
#pragma unroll
  for (int mi = 0; mi < 4; ++mi)
#pragma unroll
    for (int ni = 0; ni < 4; ++ni) {
      int e = c0 + wn + ni * 16 + l16;
      float bias = ob[e];
#pragma unroll
      for (int i = 0; i < 4; ++i) {
        int t = t0 + wm + mi * 16 + lq * 4 + i;
        out[(size_t)t * 512 + e] = acc[mi][ni][i] + bias + x[(size_t)t * 512 + e];
      }
    }
}

// ---------- launch ----------
extern "C" void kernel_launch(void* const* d_in, const int* in_sizes, int n_in,
                              void* d_out, int out_size, void* d_ws, size_t ws_size,
                              hipStream_t stream) {
  const float* x    = (const float*)d_in[0];
  const float* rpb  = (const float*)d_in[1];
  const float* mask = (const float*)d_in[2];
  const float* uvqk = (const float*)d_in[3];
  const float* o_w  = (const float*)d_in[4];
  const float* o_b  = (const float*)d_in[5];
  float* out = (float*)d_out;

  char* p = (char*)d_ws;
  short* xn   = (short*)p; p += 16384ull * 512 * 2;       // 16 MB (reused as gated)
  short* Wt   = (short*)p; p += 2048ull * 512 * 2;        // 2 MB
  short* owt  = (short*)p; p += 512ull * 512 * 2;         // 0.5 MB
  short* proj = (short*)p; p += 16384ull * 2048 * 2;      // 64 MB
  short* Vt   = (short*)p; p += 8ull * 8 * 64 * 2048 * 2; // 16 MB
  float* attn = (float*)p; p += 16384ull * 512 * 4;       // 32 MB
  short* gated = xn;

  k_ln    <<<4096, 256, 0, stream>>>(x, xn);
  k_prep_w<<<dim3(8, 32), 256, 0, stream>>>(uvqk, Wt);
  k_cast_ow<<<1024, 256, 0, stream>>>(o_w, owt);
  k_gemm1 <<<dim3(16, 128), 256, 0, stream>>>(xn, Wt, proj, Vt);
  k_attn  <<<2048, 256, 0, stream>>>(proj, Vt, rpb, mask, attn);
  k_gate  <<<4096, 256, 0, stream>>>(attn, proj, gated);
  k_gemm2 <<<dim3(4, 128), 256, 0, stream>>>(gated, owt, o_b, x, out);
}

// Round 8
// 368.969 us; speedup vs baseline: 1.2945x; 1.1188x over previous
//
#include <hip/hip_runtime.h>
#include <stdint.h>

// ---------- types ----------
typedef short bf16x8   __attribute__((ext_vector_type(8)));
typedef short short4v  __attribute__((ext_vector_type(4)));
typedef short short8v  __attribute__((ext_vector_type(8)));
typedef float f32x4    __attribute__((ext_vector_type(4)));

typedef __attribute__((address_space(3))) uint32_t lds_u32;
typedef const __attribute__((address_space(1))) uint32_t glob_u32;

__device__ __forceinline__ void gl_lds16(const void* g, void* l) {
  __builtin_amdgcn_global_load_lds((glob_u32*)g, (lds_u32*)l, 16, 0, 0);
}

__device__ __forceinline__ float bf2f(short u) {
  union { float f; uint32_t i; } v; v.i = ((uint32_t)(uint16_t)u) << 16; return v.f;
}
__device__ __forceinline__ short f2bf(float f) {
  union { float f; uint32_t i; } v; v.f = f;
  uint32_t r = v.i + 0x7FFFu + ((v.i >> 16) & 1u);
  return (short)(r >> 16);
}
__device__ __forceinline__ float siluf(float x) {
  return x * __builtin_amdgcn_rcpf(1.0f + __expf(-x));
}
__device__ __forceinline__ f32x4 mfma16(bf16x8 a, bf16x8 b, f32x4 c) {
  return __builtin_amdgcn_mfma_f32_16x16x32_bf16(a, b, c, 0, 0, 0);
}
__device__ __forceinline__ uint32_t cvtpk_bf16(float lo, float hi) {
  uint32_t d;
  asm("v_cvt_pk_bf16_f32 %0, %1, %2" : "=v"(d) : "v"(lo), "v"(hi));
  return d;
}

// ---------- K1: LayerNorm(x) -> bf16 ----------
__global__ __launch_bounds__(256) void k_ln(const float* __restrict__ x, short* __restrict__ xn) {
  int row = blockIdx.x * 4 + (threadIdx.x >> 6);
  int lane = threadIdx.x & 63;
  const float4* xr = (const float4*)(x + (size_t)row * 512);
  float4 a = xr[lane * 2], b = xr[lane * 2 + 1];
  float s  = a.x + a.y + a.z + a.w + b.x + b.y + b.z + b.w;
  float s2 = a.x*a.x + a.y*a.y + a.z*a.z + a.w*a.w + b.x*b.x + b.y*b.y + b.z*b.z + b.w*b.w;
#pragma unroll
  for (int m = 1; m < 64; m <<= 1) { s += __shfl_xor(s, m); s2 += __shfl_xor(s2, m); }
  float mu = s * (1.f / 512.f);
  float rstd = rsqrtf(s2 * (1.f / 512.f) - mu * mu + 1e-6f);
  float v[8] = {a.x, a.y, a.z, a.w, b.x, b.y, b.z, b.w};
  short8v o;
#pragma unroll
  for (int j = 0; j < 8; ++j) o[j] = f2bf((v[j] - mu) * rstd);
  *(short8v*)&xn[(size_t)row * 512 + lane * 8] = o;
}

// ---------- K2: transpose+cast uvqk (512x2048) -> Wt (2048x512) bf16; also init flag=1 ----------
__global__ __launch_bounds__(256) void k_prep_w(const float* __restrict__ uvqk, short* __restrict__ Wt,
                                                int* __restrict__ flag) {
  if (blockIdx.x == 0 && blockIdx.y == 0 && threadIdx.x == 0) *flag = 1;
  __shared__ float t[64][65];
  int k0 = blockIdx.x * 64;
  int c0 = blockIdx.y * 64;
  for (int i = threadIdx.x; i < 64 * 64; i += 256) {
    int r = i >> 6, c = i & 63;
    t[r][c] = uvqk[(size_t)(k0 + r) * 2048 + c0 + c];
  }
  __syncthreads();
  for (int i = threadIdx.x; i < 64 * 64; i += 256) {
    int c = i >> 6, k = i & 63;
    Wt[(size_t)(c0 + c) * 512 + k0 + k] = f2bf(t[k][c]);
  }
}

// ---------- K2b: cast o_w ----------
__global__ __launch_bounds__(256) void k_cast_ow(const float* __restrict__ ow, short* __restrict__ owt) {
  int i = blockIdx.x * 256 + threadIdx.x;
  owt[i] = f2bf(ow[i]);
}

// ---------- K2c: rpb -> bf16 cast + mask all-ones scan (single streaming pass) ----------
__global__ __launch_bounds__(256) void k_prep_rm(const float* __restrict__ rpb, const float* __restrict__ mask,
                                                 short* __restrict__ rpbh, int* __restrict__ flag) {
  bool ok = true;
  for (int i = blockIdx.x * 256 + threadIdx.x; i < 4194304; i += 2048 * 256) {
    const float4* r4 = (const float4*)rpb + (size_t)i * 2;
    float4 a = r4[0], b = r4[1];
    float v[8] = {a.x, a.y, a.z, a.w, b.x, b.y, b.z, b.w};
    short8v o;
#pragma unroll
    for (int j = 0; j < 8; ++j) o[j] = f2bf(v[j]);
    *(short8v*)&rpbh[(size_t)i * 8] = o;
    const float4* m4 = (const float4*)mask + (size_t)i * 2;
    float4 ma = m4[0], mb = m4[1];
    ok = ok && (ma.x == 1.f) && (ma.y == 1.f) && (ma.z == 1.f) && (ma.w == 1.f)
            && (mb.x == 1.f) && (mb.y == 1.f) && (mb.z == 1.f) && (mb.w == 1.f);
  }
  if (!ok) *flag = 0;   // benign race: many lanes store 0
}

// ---------- shared GEMM core: 128x128 tile, K=512, BK=64, 4 waves ----------
__device__ __forceinline__ void gemm_core(const short* __restrict__ A, const short* __restrict__ Bt,
                                          int t0, int c0, short* As, short* Bs, f32x4 (&acc)[4][4]) {
  int tid = threadIdx.x;
  int w = tid >> 6, lane = tid & 63, l16 = lane & 15, lq = lane >> 4;
  int wm = (w >> 1) * 64, wn = (w & 1) * 64;
  int srow = tid >> 3;
  int sch = (tid & 7) ^ (srow & 7);
  const short* ag = A  + (size_t)(t0 + srow) * 512 + sch * 8;
  const short* bg = Bt + (size_t)(c0 + srow) * 512 + sch * 8;

  for (int k0 = 0; k0 < 512; k0 += 64) {
#pragma unroll
    for (int j = 0; j < 4; ++j) {
      gl_lds16(ag + (size_t)j * 32 * 512 + k0, (char*)As + j * 4096 + w * 1024);
      gl_lds16(bg + (size_t)j * 32 * 512 + k0, (char*)Bs + j * 4096 + w * 1024);
    }
    asm volatile("s_waitcnt vmcnt(0)" ::: "memory");
    __syncthreads();
#pragma unroll
    for (int kk = 0; kk < 2; ++kk) {
      bf16x8 af[4], bf[4];
#pragma unroll
      for (int mi = 0; mi < 4; ++mi) {
        int row = wm + mi * 16 + l16;
        af[mi] = *(const bf16x8*)&As[row * 64 + (((kk * 4 + lq) ^ (l16 & 7)) * 8)];
      }
#pragma unroll
      for (int ni = 0; ni < 4; ++ni) {
        int row = wn + ni * 16 + l16;
        bf[ni] = *(const bf16x8*)&Bs[row * 64 + (((kk * 4 + lq) ^ (l16 & 7)) * 8)];
      }
#pragma unroll
      for (int mi = 0; mi < 4; ++mi)
#pragma unroll
        for (int ni = 0; ni < 4; ++ni)
          acc[mi][ni] = mfma16(af[mi], bf[ni], acc[mi][ni]);
    }
    __syncthreads();
  }
}

// ---------- K3: proj = silu(xn @ Wt^T); v written transposed to Vt[b,h,d,n] ----------
__global__ __launch_bounds__(256) void k_gemm1(const short* __restrict__ A, const short* __restrict__ Bt,
                                               short* __restrict__ proj, short* __restrict__ Vt) {
  __shared__ short As[128 * 64], Bs[128 * 64];
  int c0 = blockIdx.x * 128, t0 = blockIdx.y * 128;
  f32x4 acc[4][4] = {};
  gemm_core(A, Bt, t0, c0, As, Bs, acc);
  int tid = threadIdx.x, w = tid >> 6, lane = tid & 63, l16 = lane & 15, lq = lane >> 4;
  int wm = (w >> 1) * 64, wn = (w & 1) * 64;
  bool isv = (c0 >= 512 && c0 < 1024);
#pragma unroll
  for (int mi = 0; mi < 4; ++mi)
#pragma unroll
    for (int ni = 0; ni < 4; ++ni) {
      int c = c0 + wn + ni * 16 + l16;
      int trow = t0 + wm + mi * 16 + lq * 4;
      if (isv) {
        int hh = (c - 512) >> 6, d = (c - 512) & 63;
        int bb = trow >> 11, nn = trow & 2047;
        short4v pv;
#pragma unroll
        for (int i = 0; i < 4; ++i) pv[i] = f2bf(siluf(acc[mi][ni][i]));
        *(short4v*)&Vt[((size_t)(bb * 8 + hh) * 64 + d) * 2048 + nn] = pv;
      } else {
#pragma unroll
        for (int i = 0; i < 4; ++i)
          proj[(size_t)(trow + i) * 2048 + c] = f2bf(siluf(acc[mi][ni][i]));
      }
    }
}

// ---------- K4: fused attention ----------
// Round-7 validated schedule (BQ=64, 4 waves, dbuf K/V, 1 barrier/iter, swapped QK^T,
// cross-iter register prefetch, cvt_pk Ps). New:
//  - rpb read as bf16 (BF=true) from precast buffer (64 MB working set, L3-resident)
//  - mask loads skipped entirely when *flag==1 (all-ones mask), via uniform branch
//  - XCD swizzle keyed for K/V reuse: each XCD gets one h; consecutive ranks walk qt
//    within an (h,b) pair so the 512 KB K/V panel stays L2-hot.
template<bool BF>
__global__ __launch_bounds__(256, 4) void k_attn(const short* __restrict__ proj,
                                                 const short* __restrict__ Vt,
                                                 const void* __restrict__ rpbp,
                                                 const float* __restrict__ maskp,
                                                 const int* __restrict__ flag,
                                                 float* __restrict__ attn) {
  __shared__ __align__(16) short Ks[2][64 * 64];   // [buf][kv][d], 16B-chunk ^= kv&7
  __shared__ __align__(16) short Vs[2][64 * 64];   // [buf][d][kv], 16B-chunk ^= d&7
  __shared__ __align__(16) short Ps[64 * 64];      // [q][kv] bf16, 16B-chunk ^= (q&7)

  int p = blockIdx.x;                  // 2048 blocks
  int L = (p & 7) * 256 + (p >> 3);    // chunked XCD swizzle (2048 % 8 == 0)
  int qt = L & 31, hb = L >> 5;        // qt fastest within an XCD -> K/V L2-hot
  int h = hb >> 3, b = hb & 7;
  int n0 = qt * 64;

  int tid = threadIdx.x;
  int w = tid >> 6, lane = tid & 63, l16 = lane & 15, lq = lane >> 4;

  bool use_mask = true;
  if (BF) use_mask = (*flag == 0);     // uniform scalar branch

  // Q fragments (B-operand of swapped QK: col = l16 = q); wave owns rows n0+w*16..+15
  bf16x8 qf[2];
#pragma unroll
  for (int kk = 0; kk < 2; ++kk) {
    int n = n0 + w * 16 + l16;
    qf[kk] = *(const bf16x8*)&proj[(size_t)(b * 2048 + n) * 2048 + 1024 + h * 64 + kk * 32 + lq * 8];
  }

  // staging lane constants (pre-swizzled global source -> linear LDS dest)
  int j8 = lane >> 3, c8 = lane & 7;
  int srcc = (c8 ^ j8) * 8;
  const short* kg = proj + (size_t)(b * 2048) * 2048 + 1536 + h * 64 + srcc;
  const short* vg = Vt + (size_t)((b * 8 + h) * 64) * 2048 + srcc;

  // rpb/mask per-thread element base: (q = n0+w*16+l16, kv = kv0+ni*16+lq*4+i)
  size_t rmoff = (size_t)h * 4194304 + (size_t)(n0 + w * 16 + l16) * 2048 + lq * 4;
  const short* rp_h = (const short*)rpbp + rmoff;
  const float* rp_f = (const float*)rpbp + rmoff;
  const float* mk_t = maskp + (size_t)b * 4194304 + (size_t)(n0 + w * 16 + l16) * 2048 + lq * 4;

  f32x4 acc_o[4] = {};
  short4v rvh[4];
  f32x4   rvf[4];
  f32x4   mv[4];
#pragma unroll
  for (int ni = 0; ni < 4; ++ni) mv[ni] = (f32x4){1.f, 1.f, 1.f, 1.f};

  // ---- prologue: stage buf0 + prefetch rpb(/mask) for t=0 ----
#pragma unroll
  for (int j = 0; j < 2; ++j) {
    gl_lds16(kg + (size_t)(w * 16 + j * 8 + j8) * 2048, &Ks[0][w * 1024 + j * 512]);
    gl_lds16(vg + (size_t)(w * 16 + j * 8 + j8) * 2048, &Vs[0][w * 1024 + j * 512]);
  }
  __builtin_amdgcn_sched_barrier(0);
#pragma unroll
  for (int ni = 0; ni < 4; ++ni) {
    if (BF) rvh[ni] = *(const short4v*)(rp_h + ni * 16);
    else    rvf[ni] = *(const f32x4*)(rp_f + ni * 16);
  }
  if (use_mask) {
#pragma unroll
    for (int ni = 0; ni < 4; ++ni) mv[ni] = *(const f32x4*)(mk_t + ni * 16);
  }
  __builtin_amdgcn_sched_barrier(0);
  if (use_mask) asm volatile("s_waitcnt vmcnt(8)" ::: "memory");
  else          asm volatile("s_waitcnt vmcnt(4)" ::: "memory");
  __builtin_amdgcn_sched_barrier(0);
  __builtin_amdgcn_s_barrier();

  for (int t = 0; t < 32; ++t) {
    int kv0 = t << 6;
    const short* Kc = Ks[t & 1];
    const short* Vc = Vs[t & 1];

    // (a) stage next K/V tile
    if (t < 31) {
      short* Kn = Ks[(t & 1) ^ 1];
      short* Vn = Vs[(t & 1) ^ 1];
      int kvn = kv0 + 64;
#pragma unroll
      for (int j = 0; j < 2; ++j) {
        gl_lds16(kg + (size_t)(kvn + w * 16 + j * 8 + j8) * 2048, &Kn[w * 1024 + j * 512]);
        gl_lds16(vg + (size_t)(w * 16 + j * 8 + j8) * 2048 + kvn, &Vn[w * 1024 + j * 512]);
      }
    }
    __builtin_amdgcn_sched_barrier(0);

    // (b) QK^T (swapped: A = K rows = kv, B = Q cols = q)
    f32x4 s[4];
#pragma unroll
    for (int ni = 0; ni < 4; ++ni) s[ni] = (f32x4){0.f, 0.f, 0.f, 0.f};
    __builtin_amdgcn_s_setprio(1);
#pragma unroll
    for (int kk = 0; kk < 2; ++kk) {
      bf16x8 kf[4];
#pragma unroll
      for (int ni = 0; ni < 4; ++ni)
        kf[ni] = *(const bf16x8*)&Kc[(ni * 16 + l16) * 64 + (((kk * 4 + lq) ^ (l16 & 7)) * 8)];
#pragma unroll
      for (int ni = 0; ni < 4; ++ni)
        s[ni] = mfma16(kf[ni], qf[kk], s[ni]);
    }
    __builtin_amdgcn_s_setprio(0);

    // (c) epilogue: p = silu(s + rpb) * mask -> Ps (cvt_pk packed, swizzled)
    {
      int row = w * 16 + l16;
      char* pr = (char*)Ps + row * 128;
      int swz = (l16 & 7) << 4;
#pragma unroll
      for (int ni = 0; ni < 4; ++ni) {
        float pv[4];
#pragma unroll
        for (int i = 0; i < 4; ++i) {
          float r = BF ? bf2f(rvh[ni][i]) : rvf[ni][i];
          float xx = s[ni][i] + r;
          pv[i] = siluf(xx) * mv[ni][i];
        }
        union { uint32_t u[2]; short4v sv; } pk;
        pk.u[0] = cvtpk_bf16(pv[0], pv[1]);
        pk.u[1] = cvtpk_bf16(pv[2], pv[3]);
        *(short4v*)(pr + ((ni * 32 + lq * 8) ^ swz)) = pk.sv;
      }
    }

    // (d) PV (Ps rows wave-private; compiler orders LDS deps)
    __builtin_amdgcn_s_setprio(1);
#pragma unroll
    for (int ks = 0; ks < 2; ++ks) {
      bf16x8 pf, vf[4];
      {
        int rp = w * 16 + l16;
        pf = *(const bf16x8*)((const char*)Ps + rp * 128 + (((ks * 4 + lq) << 4) ^ ((l16 & 7) << 4)));
      }
#pragma unroll
      for (int ni = 0; ni < 4; ++ni)
        vf[ni] = *(const bf16x8*)&Vc[(ni * 16 + l16) * 64 + (((ks * 4 + lq) ^ (l16 & 7)) * 8)];
#pragma unroll
      for (int ni = 0; ni < 4; ++ni)
        acc_o[ni] = mfma16(pf, vf[ni], acc_o[ni]);
    }
    __builtin_amdgcn_s_setprio(0);

    // (e) prefetch rpb(/mask) for t+1 (full-iteration latency cover)
    __builtin_amdgcn_sched_barrier(0);
    {
      int kvp = (t < 31) ? kv0 + 64 : kv0;
#pragma unroll
      for (int ni = 0; ni < 4; ++ni) {
        if (BF) rvh[ni] = *(const short4v*)(rp_h + kvp + ni * 16);
        else    rvf[ni] = *(const f32x4*)(rp_f + kvp + ni * 16);
      }
      if (use_mask) {
#pragma unroll
        for (int ni = 0; ni < 4; ++ni) mv[ni] = *(const f32x4*)(mk_t + kvp + ni * 16);
      }
    }
    __builtin_amdgcn_sched_barrier(0);
    // (f) drain only the 4 gl_lds; the prefetch loads stay in flight across the barrier
    if (use_mask) asm volatile("s_waitcnt vmcnt(8)" ::: "memory");
    else          asm volatile("s_waitcnt vmcnt(4)" ::: "memory");
    __builtin_amdgcn_sched_barrier(0);
    __builtin_amdgcn_s_barrier();
  }

  // store: q = n0 + w*16 + lq*4 + i (D-frag row), d = ni*16 + l16 (D-frag col)
#pragma unroll
  for (int ni = 0; ni < 4; ++ni)
#pragma unroll
    for (int i = 0; i < 4; ++i) {
      int n = n0 + w * 16 + lq * 4 + i;
      attn[(size_t)(b * 2048 + n) * 512 + h * 64 + ni * 16 + l16] = acc_o[ni][i];
    }
}

// ---------- K5: gated = u * LayerNorm(attn) -> bf16 ----------
__global__ __launch_bounds__(256) void k_gate(const float* __restrict__ attn, const short* __restrict__ proj,
                                              short* __restrict__ gated) {
  int row = blockIdx.x * 4 + (threadIdx.x >> 6);
  int lane = threadIdx.x & 63;
  const float4* ar = (const float4*)(attn + (size_t)row * 512);
  float4 a = ar[lane * 2], b = ar[lane * 2 + 1];
  float s  = a.x + a.y + a.z + a.w + b.x + b.y + b.z + b.w;
  float s2 = a.x*a.x + a.y*a.y + a.z*a.z + a.w*a.w + b.x*b.x + b.y*b.y + b.z*b.z + b.w*b.w;
#pragma unroll
  for (int m = 1; m < 64; m <<= 1) { s += __shfl_xor(s, m); s2 += __shfl_xor(s2, m); }
  float mu = s * (1.f / 512.f);
  float rstd = rsqrtf(s2 * (1.f / 512.f) - mu * mu + 1e-6f);
  float v[8] = {a.x, a.y, a.z, a.w, b.x, b.y, b.z, b.w};
  short8v u = *(const short8v*)&proj[(size_t)row * 2048 + lane * 8];
  short8v g;
#pragma unroll
  for (int j = 0; j < 8; ++j) g[j] = f2bf(bf2f(u[j]) * ((v[j] - mu) * rstd));
  *(short8v*)&gated[(size_t)row * 512 + lane * 8] = g;
}

// ---------- K6: out = gated @ owt^T + o_b + x ----------
__global__ __launch_bounds__(256) void k_gemm2(const short* __restrict__ A, const short* __restrict__ Bt,
                                               const float* __restrict__ ob, const float* __restrict__ x,
                                               float* __restrict__ out) {
  __shared__ short As[128 * 64], Bs[128 * 64];
  int c0 = blockIdx.x * 128, t0 = blockIdx.y * 128;
  f32x4 acc[4][4] = {};
  gemm_core(A, Bt, t0, c0, As, Bs, acc);
  int tid = threadIdx.x, w = tid >> 6, lane = tid & 63, l16 = lane & 15, lq = lane >> 4;
  int wm = (w >> 1) * 64, wn = (w & 1) * 64;
#pragma unroll
  for (int mi = 0; mi < 4; ++mi)
#pragma unroll
    for (int ni = 0; ni < 4; ++ni) {
      int e = c0 + wn + ni * 16 + l16;
      float bias = ob[e];
#pragma unroll
      for (int i = 0; i < 4; ++i) {
        int t = t0 + wm + mi * 16 + lq * 4 + i;
        out[(size_t)t * 512 + e] = acc[mi][ni][i] + bias + x[(size_t)t * 512 + e];
      }
    }
}

// ---------- launch ----------
extern "C" void kernel_launch(void* const* d_in, const int* in_sizes, int n_in,
                              void* d_out, int out_size, void* d_ws, size_t ws_size,
                              hipStream_t stream) {
  const float* x    = (const float*)d_in[0];
  const float* rpb  = (const float*)d_in[1];
  const float* mask = (const float*)d_in[2];
  const float* uvqk = (const float*)d_in[3];
  const float* o_w  = (const float*)d_in[4];
  const float* o_b  = (const float*)d_in[5];
  float* out = (float*)d_out;

  char* p = (char*)d_ws;
  short* xn   = (short*)p; p += 16384ull * 512 * 2;       // 16 MB (reused as gated)
  short* Wt   = (short*)p; p += 2048ull * 512 * 2;        // 2 MB
  short* owt  = (short*)p; p += 512ull * 512 * 2;         // 0.5 MB
  short* proj = (short*)p; p += 16384ull * 2048 * 2;      // 64 MB
  short* Vt   = (short*)p; p += 8ull * 8 * 64 * 2048 * 2; // 16 MB
  float* attn = (float*)p; p += 16384ull * 512 * 4;       // 32 MB
  short* rpbh = (short*)p; p += 33554432ull * 2;          // 64 MB (bf16 rpb)
  int*   flag = (int*)p;   p += 256;                      // all-ones-mask flag
  short* gated = xn;

  bool bf_ok = ws_size >= (size_t)(p - (char*)d_ws);

  k_ln    <<<4096, 256, 0, stream>>>(x, xn);
  k_prep_w<<<dim3(8, 32), 256, 0, stream>>>(uvqk, Wt, bf_ok ? flag : (int*)attn);
  k_cast_ow<<<1024, 256, 0, stream>>>(o_w, owt);
  if (bf_ok)
    k_prep_rm<<<2048, 256, 0, stream>>>(rpb, mask, rpbh, flag);
  k_gemm1 <<<dim3(16, 128), 256, 0, stream>>>(xn, Wt, proj, Vt);
  if (bf_ok)
    k_attn<true> <<<2048, 256, 0, stream>>>(proj, Vt, rpbh, mask, flag, attn);
  else
    k_attn<false><<<2048, 256, 0, stream>>>(proj, Vt, rpb, mask, (const int*)attn, attn);
  k_gate  <<<4096, 256, 0, stream>>>(attn, proj, gated);
  k_gemm2 <<<dim3(4, 128), 256, 0, stream>>>(gated, owt, o_b, x, out);
}